// Round 1
// 161.568 us; speedup vs baseline: 1.0278x; 1.0278x over previous
//
#include <hip/hip_runtime.h>
#include <hip/hip_bf16.h>

// Problem constants
#define BB 8
#define NN 8192
#define CC 64
#define PP 2048
#define KK 16
#define H1 64
#define H2 128
#define K2PAD 72

typedef float  f32x4 __attribute__((ext_vector_type(4)));
typedef short  s16x8 __attribute__((ext_vector_type(8)));

// ---- workspace layout (bytes) ----
// fxtb: B*N rows of 72 bf16 (144 B, 16B-aligned) = 9,437,184 bytes
#define OFF_FXT   0u
#define OFF_PTS4  17825792u             // B*N float4 = 2,097,152
#define OFF_KNN   19922944u             // B*P*16 int  = 1,048,576
#define OFF_W1P   20971520u             // 64*192 bf16 = 24,576  ([n][0:96)=W1a*s, [n][96:192)=(W1b-W1a)*s)
#define OFF_W2P   20996096u             // 128*72 bf16 = 18,432
#define OFF_C1    21014528u             // 64 f32
#define OFF_C2    21014784u             // 128 f32

#define FLTMAX 3.402823466e+38f

static __device__ __forceinline__ unsigned short bf16b(float v) {
    __hip_bfloat16 h = __float2bfloat16(v);
    return *reinterpret_cast<unsigned short*>(&h);
}
static __device__ __forceinline__ unsigned pk2(float a, float b) {
    return ((unsigned)bf16b(b) << 16) | (unsigned)bf16b(a);
}
static __device__ __forceinline__ s16x8 as8(uint4 v) {
    union { uint4 u; s16x8 s; } x; x.u = v; return x.s;
}
// wave-local LDS fence: compiler barrier + LDS drain, NO vmcnt drain
#define LDS_FENCE() asm volatile("s_waitcnt lgkmcnt(0)" ::: "memory")

// ---------------- K1: transpose feat -> fxtb (bf16 rows of 72), pts4, outs ----
__global__ __launch_bounds__(512) void k1_prep(const float* __restrict__ xyz,
                                               const float* __restrict__ feat,
                                               unsigned* __restrict__ fxtb,
                                               float4* __restrict__ pts4,
                                               float* __restrict__ out0,
                                               float* __restrict__ out2) {
    __shared__ float tile[72][65];
    int b  = blockIdx.x >> 7;
    int n0 = (blockIdx.x & 127) * 64;
    int tx = threadIdx.x & 63, ty = threadIdx.x >> 6;
    for (int c = ty; c < 72; c += 8) {
        float v;
        if (c < 64)       v = feat[((size_t)b * 64 + c) * NN + n0 + tx];
        else if (c < 67)  v = xyz[((size_t)b * NN + n0 + tx) * 3 + (c - 64)];
        else              v = 0.f;                 // pad cols 67..71
        tile[c][tx] = v;
    }
    __syncthreads();
    size_t base = ((size_t)b * NN + n0) * 36;      // 36 dwords (72 bf16) per row
    for (int e = threadIdx.x; e < 64 * 36; e += 512) {
        int nl = e / 36, c = e - nl * 36;
        fxtb[base + e] = pk2(tile[2 * c][nl], tile[2 * c + 1][nl]);
    }
    if (threadIdx.x < 64) {
        int n = n0 + threadIdx.x;
        float x = tile[64][threadIdx.x], y = tile[65][threadIdx.x], z = tile[66][threadIdx.x];
        pts4[(size_t)b * NN + n] = make_float4(x, y, z, x * x + y * y + z * z);
        if (n0 < PP) out2[b * PP + n] = (float)n;
    }
    if (n0 < PP) {
        for (int e = threadIdx.x; e < 64 * 3; e += 512) {
            int nl = e / 3, d = e - nl * 3;
            out0[((size_t)b * PP + n0 + nl) * 3 + d] = tile[64 + d][nl];
        }
    }
}

// ---------------- K2 v5 + inlined weight fold ----
// 256 blocks x 1024 thr, whole batch staged once (128 KB), one barrier.
// Weight folding (21,696 elems) sliced 85/block, hidden in staging latency.
// Fold now writes W1a*s and W1d=(W1b-W1a)*s halves (k3 uses the identity
// E*W1^T = f_k*W1a^T + f_q*W1d^T, so the edge matrix is never built).
__global__ __launch_bounds__(1024, 2) void k2_knn(const float4* __restrict__ pts4,
                                                  int* __restrict__ knn,
                                                  const float* __restrict__ W1, const float* __restrict__ b1,
                                                  const float* __restrict__ g1, const float* __restrict__ be1,
                                                  const float* __restrict__ m1, const float* __restrict__ v1,
                                                  const float* __restrict__ W2, const float* __restrict__ b2,
                                                  const float* __restrict__ g2, const float* __restrict__ be2,
                                                  const float* __restrict__ m2, const float* __restrict__ v2,
                                                  unsigned short* __restrict__ w1p,
                                                  unsigned short* __restrict__ w2p,
                                                  float* __restrict__ c1, float* __restrict__ c2) {
    __shared__ float4 stage[8192];           // 128 KB
    __shared__ float2 scratch[16][2][64];    // 16 KB dual per-wave buffers
    int lane = threadIdx.x & 63;
    int wv   = threadIdx.x >> 6;
    int b    = blockIdx.x >> 5;
    int q0   = (blockIdx.x & 31) * 64 + wv * 4;
    size_t pb = (size_t)b * NN;

    float4 qc = make_float4(0.f, 0.f, 0.f, 0.f);
    if (lane < 4) qc = pts4[pb + q0 + lane];
    float qx2 = -2.f * qc.x, qy2 = -2.f * qc.y, qz2 = -2.f * qc.z;
    float bx[4], by[4], bz[4];
#pragma unroll
    for (int q = 0; q < 4; ++q) {
        bx[q] = __shfl(qx2, q); by[q] = __shfl(qy2, q); bz[q] = __shfl(qz2, q);
    }

    // stage all 8192 points, swizzled slot(r,c) = r*64 + ((c + (r>>1)) & 63)
#pragma unroll
    for (int i = 0; i < 8; ++i) {
        int p = i * 1024 + threadIdx.x;
        float4 v = pts4[pb + p];
        int r = p >> 6, c = p & 63;
        stage[(r << 6) | ((c + (r >> 1)) & 63)] = v;
    }

    // weight fold slice: 85 elems/block, hidden in staging latency
    if (threadIdx.x < 85) {
        int i = blockIdx.x * 85 + threadIdx.x;
        if (i < 6144) {                      // W1a folded: [64][96]
            int n = i / 96, c = i - n * 96;
            float s = g1[n] * rsqrtf(v1[n] + 1e-5f);
            w1p[n * 192 + c] = bf16b((c < 67) ? W1[n * 134 + c] * s : 0.f);
        } else if (i < 12288) {              // W1d folded: [64][96] at +96
            int j = i - 6144;
            int n = j / 96, c = j - n * 96;
            float s = g1[n] * rsqrtf(v1[n] + 1e-5f);
            w1p[n * 192 + 96 + c] =
                bf16b((c < 67) ? (W1[n * 134 + 67 + c] - W1[n * 134 + c]) * s : 0.f);
        } else if (i < 21504) {              // W2 folded: [128][72]
            int j = i - 12288;
            int o = j / 72, k = j - o * 72;
            float s = g2[o] * rsqrtf(v2[o] + 1e-5f);
            w2p[j] = bf16b((k < 64) ? W2[o * 64 + k] * s : 0.f);
        } else if (i < 21568) {
            int l = i - 21504;
            float s = g1[l] * rsqrtf(v1[l] + 1e-5f);
            c1[l] = s * (b1[l] - m1[l]) + be1[l];
        } else if (i < 21696) {
            int p = i - 21568;
            float s = g2[p] * rsqrtf(v2[p] + 1e-5f);
            c2[p] = s * (b2[p] - m2[p]) + be2[p];
        }
    }
    __syncthreads();   // the only block barrier

    // Phase 1: per-lane min over its 128 candidates (rows 2L, 2L+1)
    float m[4];
#pragma unroll
    for (int q = 0; q < 4; ++q) m[q] = FLTMAX;
#pragma unroll
    for (int rr = 0; rr < 2; ++rr) {
        int rowbase = (2 * lane + rr) << 6;
#pragma unroll
        for (int j8 = 0; j8 < 8; ++j8) {
            float4 cc[8];
#pragma unroll
            for (int i = 0; i < 8; ++i)
                cc[i] = stage[rowbase | ((j8 * 8 + i + lane) & 63)];
#pragma unroll
            for (int q = 0; q < 4; ++q) {
                float x = bx[q], y = by[q], z = bz[q];
#pragma unroll
                for (int i = 0; i < 8; i += 2) {
                    float e0 = fmaf(z, cc[i].z, fmaf(y, cc[i].y, fmaf(x, cc[i].x, cc[i].w)));
                    float e1 = fmaf(z, cc[i+1].z, fmaf(y, cc[i+1].y, fmaf(x, cc[i+1].x, cc[i+1].w)));
                    m[q] = fminf(fminf(m[q], e0), e1);
                }
            }
        }
    }

    // Interleaved threshold sorts: T[q] = 16th smallest of 64 lane-mins
    float sv0 = m[0], sv1 = m[1], sv2 = m[2], sv3 = m[3];
#pragma unroll
    for (int k = 2; k <= 64; k <<= 1) {
#pragma unroll
        for (int j = k >> 1; j > 0; j >>= 1) {
            bool keepMin = (((lane & k) == 0) == ((lane & j) == 0));
            float p0 = __shfl_xor(sv0, j, 64);
            float p1 = __shfl_xor(sv1, j, 64);
            float p2 = __shfl_xor(sv2, j, 64);
            float p3 = __shfl_xor(sv3, j, 64);
            sv0 = keepMin ? fminf(sv0, p0) : fmaxf(sv0, p0);
            sv1 = keepMin ? fminf(sv1, p1) : fmaxf(sv1, p1);
            sv2 = keepMin ? fminf(sv2, p2) : fmaxf(sv2, p2);
            sv3 = keepMin ? fminf(sv3, p3) : fmaxf(sv3, p3);
        }
    }
    float T[4];
    T[0] = __shfl(sv0, 15, 64); T[1] = __shfl(sv1, 15, 64);
    T[2] = __shfl(sv2, 15, 64); T[3] = __shfl(sv3, 15, 64);

    unsigned long long below = (lane == 63) ? 0x7FFFFFFFFFFFFFFFull
                                            : ((1ull << lane) - 1ull);
#pragma unroll
    for (int pr = 0; pr < 4; pr += 2) {
        int Ms[2];
        // rescan + ballot-prefix compaction into dual scratch buffers
#pragma unroll
        for (int u = 0; u < 2; ++u) {
            int q = pr + u;
            float x = bx[q], y = by[q], z = bz[q], tq = T[q];
            unsigned long long rm = __ballot(m[q] <= tq);
            int cnt = 0;
            while (rm) {
                int sl = __ffsll((long long)rm) - 1; rm &= rm - 1;
                int phys = (lane + sl) & 63;
                float4 c0 = stage[((2 * sl) << 6) | phys];
                float4 c1v_ = stage[((2 * sl + 1) << 6) | phys];
                float e0 = fmaf(z, c0.z, fmaf(y, c0.y, fmaf(x, c0.x, c0.w)));
                float e1 = fmaf(z, c1v_.z, fmaf(y, c1v_.y, fmaf(x, c1v_.x, c1v_.w)));
                unsigned long long b0 = __ballot(e0 <= tq);
                if (e0 <= tq) {
                    int pos = cnt + __popcll(b0 & below);
                    if (pos < 64)
                        scratch[wv][u][pos] = make_float2(e0, __int_as_float(sl * 128 + lane));
                }
                cnt += __popcll(b0);
                unsigned long long b1 = __ballot(e1 <= tq);
                if (e1 <= tq) {
                    int pos = cnt + __popcll(b1 & below);
                    if (pos < 64)
                        scratch[wv][u][pos] = make_float2(e1, __int_as_float(sl * 128 + 64 + lane));
                }
                cnt += __popcll(b1);
            }
            Ms[u] = min(cnt, 64);
        }
        LDS_FENCE();   // drain compaction writes before readback
        // rank-select both queries (broadcast LDS reads, pipelined VALU)
#pragma unroll
        for (int u = 0; u < 2; ++u) {
            int M = Ms[u];
            float2 own = scratch[wv][u][lane];
            float di = own.x; int ni = __float_as_int(own.y);
            int rank = 0;
            const float2* buf = &scratch[wv][u][0];
#pragma unroll 4
            for (int j = 0; j < M; ++j) {
                float2 e = buf[j];
                int nj = __float_as_int(e.y);
                rank += (e.x < di || (e.x == di && nj < ni)) ? 1 : 0;
            }
            if (lane < M && rank < 16)
                knn[((size_t)(b * PP + q0 + pr + u)) * KK + rank] = ni;
        }
        LDS_FENCE();   // order scratch reuse across pairs
    }
}

// ---------------- K3 v6: edge-free MLP via qterm identity ----
// y1[edge][o] = f_k . W1a*s + f_q . W1d*s + c1   (no E matrix built)
//  - gathered neighbor rows land DIRECTLY in MFMA A-fragments:
//    row = lane&15, k-chunk = ks*4+quad  (fxtb rows = 9 uint4 chunks, k=72->pad96)
//  - per-wave qterm: one 16x16 A-tile of the wave's own 4 query rows,
//    12 MFMA for 4 queries, broadcast via shfl, folded with c1 into acc init
//  - W1a/W2 fragments persist in VGPRs (loaded once); LDS = h1 round-trip + otile
__global__ __launch_bounds__(256, 2) void k3_mlp(const unsigned* __restrict__ fxtb,
                                                 const int* __restrict__ knn,
                                                 const unsigned short* __restrict__ w1p,
                                                 const unsigned short* __restrict__ w2p,
                                                 const float* __restrict__ c1,
                                                 const float* __restrict__ c2,
                                                 float* __restrict__ out1) {
    __shared__ __align__(16) unsigned short h1l[4][16 * K2PAD];   // 9,216 B
    __shared__ float otile[16][132];                              // 8,448 B
    int lane = threadIdx.x & 63;
    int wv   = threadIdx.x >> 6;
    int b    = blockIdx.x & 7;        // XCD-aware batch assignment
    int qg   = blockIdx.x >> 3;
    int qbase = qg * 16;
    int col = lane & 15, quad = lane >> 4;
    const uint4* fx4 = (const uint4*)fxtb;
    size_t rowb = (size_t)b * NN;

    // ---- qterm: f_q . W1d for this wave's 4 queries (rows 0..3 of the tile;
    //      rows 4..15 load valid neighboring rows and are simply ignored) ----
    f32x4 accq[4];
#pragma unroll
    for (int nt = 0; nt < 4; ++nt) accq[nt] = (f32x4){0.f, 0.f, 0.f, 0.f};
    {
        const uint4* rp = fx4 + (rowb + qbase + wv * 4 + col) * 9;
        uint4 qf0 = rp[quad];
        uint4 qf1 = rp[4 + quad];
        uint4 qf2 = rp[8];
        if (quad != 0) qf2 = make_uint4(0u, 0u, 0u, 0u);
        uint4 qf[3] = {qf0, qf1, qf2};
#pragma unroll
        for (int ks = 0; ks < 3; ++ks) {
            s16x8 a = as8(qf[ks]);
#pragma unroll
            for (int nt = 0; nt < 4; ++nt) {
                s16x8 bfr = *(const s16x8*)(w1p + (nt * 16 + col) * 192 + 96 + ks * 32 + quad * 8);
                accq[nt] = __builtin_amdgcn_mfma_f32_16x16x32_bf16(a, bfr, accq[nt], 0, 0, 0);
            }
        }
    }
    float qc[4][4];   // qterm + c1, per (query, nt)
    {
        float c1v[4];
#pragma unroll
        for (int nt = 0; nt < 4; ++nt) c1v[nt] = c1[nt * 16 + col];
#pragma unroll
        for (int qi = 0; qi < 4; ++qi)
#pragma unroll
            for (int nt = 0; nt < 4; ++nt)
                qc[qi][nt] = __shfl(accq[nt][qi], col, 64) + c1v[nt];
    }

    // ---- persistent weight fragments in registers (w1df regs now dead) ----
    s16x8 w1f[3][4], w2f[2][8];
#pragma unroll
    for (int ks = 0; ks < 3; ++ks)
#pragma unroll
        for (int nt = 0; nt < 4; ++nt)
            w1f[ks][nt] = *(const s16x8*)(w1p + (nt * 16 + col) * 192 + ks * 32 + quad * 8);
#pragma unroll
    for (int ks = 0; ks < 2; ++ks)
#pragma unroll
        for (int nt = 0; nt < 8; ++nt)
            w2f[ks][nt] = *(const s16x8*)(w2p + (nt * 16 + col) * K2PAD + ks * 32 + quad * 8);
    float c2v[8];
#pragma unroll
    for (int nt = 0; nt < 8; ++nt) c2v[nt] = c2[nt * 16 + col];

    // all 64 knn indices for this wave's 4 queries (contiguous load)
    int idxAll = knn[((size_t)(b * PP + qbase + wv * 4)) * KK + lane];
    unsigned short* h1w = &h1l[wv][0];

    uint4 af[2][3];
#define PREF(buf, qi_) {                                                      \
        int nidx_ = __shfl(idxAll, (qi_) * 16 + col, 64);                     \
        const uint4* rp_ = fx4 + (rowb + nidx_) * 9;                          \
        af[buf][0] = rp_[quad];                                               \
        af[buf][1] = rp_[4 + quad];                                           \
        uint4 f2_ = rp_[8];                                                   \
        af[buf][2] = (quad == 0) ? f2_ : make_uint4(0u, 0u, 0u, 0u); }

    PREF(0, 0);

#pragma unroll
    for (int qi = 0; qi < 4; ++qi) {
        const int cur = qi & 1;
        // GEMM1: pure register MFMA, acc init = qterm + c1
        f32x4 acc1[4];
#pragma unroll
        for (int nt = 0; nt < 4; ++nt)
            acc1[nt] = (f32x4){qc[qi][nt], qc[qi][nt], qc[qi][nt], qc[qi][nt]};
#pragma unroll
        for (int ks = 0; ks < 3; ++ks) {
            s16x8 a = as8(af[cur][ks]);
#pragma unroll
            for (int nt = 0; nt < 4; ++nt)
                acc1[nt] = __builtin_amdgcn_mfma_f32_16x16x32_bf16(a, w1f[ks][nt], acc1[nt], 0, 0, 0);
        }
        // kick next query's gather while h1/GEMM2 run
        if (qi < 3) PREF(cur ^ 1, qi + 1);
        // h1 = relu(acc1) -> LDS (wave-private; prior reads drained by loop-tail fence)
#pragma unroll
        for (int nt = 0; nt < 4; ++nt)
#pragma unroll
            for (int rr = 0; rr < 4; ++rr)
                h1w[(quad * 4 + rr) * K2PAD + nt * 16 + col] = bf16b(fmaxf(acc1[nt][rr], 0.f));
        LDS_FENCE();
        // GEMM2 + maxpool over 16 edges
        f32x4 acc2[8];
#pragma unroll
        for (int nt = 0; nt < 8; ++nt) acc2[nt] = (f32x4){0.f, 0.f, 0.f, 0.f};
#pragma unroll
        for (int ks = 0; ks < 2; ++ks) {
            s16x8 a2 = *(const s16x8*)(h1w + col * K2PAD + ks * 32 + quad * 8);
#pragma unroll
            for (int nt = 0; nt < 8; ++nt)
                acc2[nt] = __builtin_amdgcn_mfma_f32_16x16x32_bf16(a2, w2f[ks][nt], acc2[nt], 0, 0, 0);
        }
#pragma unroll
        for (int nt = 0; nt < 8; ++nt) {
            float m0 = fmaxf(fmaxf(acc2[nt][0], acc2[nt][1]), fmaxf(acc2[nt][2], acc2[nt][3]));
            m0 = fmaxf(m0 + c2v[nt], 0.f);
            m0 = fmaxf(m0, __shfl_xor(m0, 16, 64));
            m0 = fmaxf(m0, __shfl_xor(m0, 32, 64));
            if (quad == 0)
                otile[wv * 4 + qi][nt * 16 + col] = m0;
        }
        LDS_FENCE();   // drain h1 reads before next iteration's overwrite
    }
    __syncthreads();
    // coalesced store: consecutive threads -> consecutive q, same channel
    for (int i = threadIdx.x; i < H2 * 16; i += 256) {
        int ch = i >> 4, q = i & 15;
        out1[((size_t)(b * H2 + ch)) * PP + qbase + q] = otile[q][ch];
    }
#undef PREF
}

extern "C" void kernel_launch(void* const* d_in, const int* in_sizes, int n_in,
                              void* d_out, int out_size, void* d_ws, size_t ws_size,
                              hipStream_t stream) {
    const float* xyz  = (const float*)d_in[0];
    const float* feat = (const float*)d_in[1];
    const float* W1   = (const float*)d_in[2];
    const float* b1   = (const float*)d_in[3];
    const float* g1   = (const float*)d_in[4];
    const float* be1  = (const float*)d_in[5];
    const float* m1   = (const float*)d_in[6];
    const float* v1   = (const float*)d_in[7];
    const float* W2   = (const float*)d_in[8];
    const float* b2   = (const float*)d_in[9];
    const float* g2   = (const float*)d_in[10];
    const float* be2  = (const float*)d_in[11];
    const float* m2   = (const float*)d_in[12];
    const float* v2   = (const float*)d_in[13];

    char* ws = (char*)d_ws;
    unsigned*       fxtb = (unsigned*)(ws + OFF_FXT);
    float4*         pts4 = (float4*)(ws + OFF_PTS4);
    int*            knn  = (int*)(ws + OFF_KNN);
    unsigned short* w1p  = (unsigned short*)(ws + OFF_W1P);
    unsigned short* w2p  = (unsigned short*)(ws + OFF_W2P);
    float*          c1   = (float*)(ws + OFF_C1);
    float*          c2   = (float*)(ws + OFF_C2);

    float* out0 = (float*)d_out;
    float* out1 = out0 + (size_t)BB * PP * 3;
    float* out2 = out1 + (size_t)BB * H2 * PP;

    hipLaunchKernelGGL(k1_prep, dim3(1024), dim3(512), 0, stream,
                       xyz, feat, fxtb, pts4, out0, out2);
    hipLaunchKernelGGL(k2_knn, dim3(256), dim3(1024), 0, stream, pts4, knn,
                       W1, b1, g1, be1, m1, v1, W2, b2, g2, be2, m2, v2,
                       w1p, w2p, c1, c2);
    hipLaunchKernelGGL(k3_mlp, dim3(1024), dim3(256), 0, stream,
                       fxtb, knn, w1p, w2p, c1, c2, out1);
}

// Round 2
// 155.277 us; speedup vs baseline: 1.0694x; 1.0405x over previous
//
#include <hip/hip_runtime.h>
#include <hip/hip_bf16.h>

// Problem constants
#define BB 8
#define NN 8192
#define CC 64
#define PP 2048
#define KK 16
#define H1 64
#define H2 128
#define K2PAD 72

typedef float  f32x4 __attribute__((ext_vector_type(4)));
typedef short  s16x8 __attribute__((ext_vector_type(8)));

// ---- workspace layout (bytes) ----
#define OFF_FXT   0u
#define OFF_PTS4  17825792u             // B*N float4 = 2,097,152
#define OFF_KNN   19922944u             // (unused now)
#define OFF_W1P   20971520u             // 64*192 bf16 ([n][0:96)=W1a*s, [n][96:192)=(W1b-W1a)*s)
#define OFF_W2P   20996096u             // 128*72 bf16
#define OFF_C1    21014528u             // 64 f32
#define OFF_C2    21014784u             // 128 f32

#define FLTMAX 3.402823466e+38f

static __device__ __forceinline__ unsigned short bf16b(float v) {
    __hip_bfloat16 h = __float2bfloat16(v);
    return *reinterpret_cast<unsigned short*>(&h);
}
static __device__ __forceinline__ unsigned pk2(float a, float b) {
    return ((unsigned)bf16b(b) << 16) | (unsigned)bf16b(a);
}
static __device__ __forceinline__ s16x8 as8(uint4 v) {
    union { uint4 u; s16x8 s; } x; x.u = v; return x.s;
}
// wave-local LDS fence: compiler barrier + LDS drain, NO vmcnt drain
#define LDS_FENCE() asm volatile("s_waitcnt lgkmcnt(0)" ::: "memory")

// ---------------- K1: transpose feat -> fxtb, pts4, outs, weight fold ----
__global__ __launch_bounds__(512) void k1_prep(const float* __restrict__ xyz,
                                               const float* __restrict__ feat,
                                               unsigned* __restrict__ fxtb,
                                               float4* __restrict__ pts4,
                                               float* __restrict__ out0,
                                               float* __restrict__ out2,
                                               const float* __restrict__ W1, const float* __restrict__ b1,
                                               const float* __restrict__ g1, const float* __restrict__ be1,
                                               const float* __restrict__ m1, const float* __restrict__ v1,
                                               const float* __restrict__ W2, const float* __restrict__ b2,
                                               const float* __restrict__ g2, const float* __restrict__ be2,
                                               const float* __restrict__ m2, const float* __restrict__ v2,
                                               unsigned short* __restrict__ w1p,
                                               unsigned short* __restrict__ w2p,
                                               float* __restrict__ c1, float* __restrict__ c2) {
    __shared__ float tile[72][65];
    // weight fold slice (21,696 elems over blocks 0..255), hidden in k1 latency
    if (blockIdx.x < 256 && threadIdx.x < 85) {
        int i = blockIdx.x * 85 + threadIdx.x;
        if (i < 6144) {                      // W1a folded: [64][96]
            int n = i / 96, c = i - n * 96;
            float s = g1[n] * rsqrtf(v1[n] + 1e-5f);
            w1p[n * 192 + c] = bf16b((c < 67) ? W1[n * 134 + c] * s : 0.f);
        } else if (i < 12288) {              // W1d = (W1b-W1a)*s: [64][96] at +96
            int j = i - 6144;
            int n = j / 96, c = j - n * 96;
            float s = g1[n] * rsqrtf(v1[n] + 1e-5f);
            w1p[n * 192 + 96 + c] =
                bf16b((c < 67) ? (W1[n * 134 + 67 + c] - W1[n * 134 + c]) * s : 0.f);
        } else if (i < 21504) {              // W2 folded: [128][72]
            int j = i - 12288;
            int o = j / 72, k = j - o * 72;
            float s = g2[o] * rsqrtf(v2[o] + 1e-5f);
            w2p[j] = bf16b((k < 64) ? W2[o * 64 + k] * s : 0.f);
        } else if (i < 21568) {
            int l = i - 21504;
            float s = g1[l] * rsqrtf(v1[l] + 1e-5f);
            c1[l] = s * (b1[l] - m1[l]) + be1[l];
        } else if (i < 21696) {
            int p = i - 21568;
            float s = g2[p] * rsqrtf(v2[p] + 1e-5f);
            c2[p] = s * (b2[p] - m2[p]) + be2[p];
        }
    }
    int b  = blockIdx.x >> 7;
    int n0 = (blockIdx.x & 127) * 64;
    int tx = threadIdx.x & 63, ty = threadIdx.x >> 6;
    for (int c = ty; c < 72; c += 8) {
        float v;
        if (c < 64)       v = feat[((size_t)b * 64 + c) * NN + n0 + tx];
        else if (c < 67)  v = xyz[((size_t)b * NN + n0 + tx) * 3 + (c - 64)];
        else              v = 0.f;                 // pad cols 67..71
        tile[c][tx] = v;
    }
    __syncthreads();
    size_t base = ((size_t)b * NN + n0) * 36;      // 36 dwords (72 bf16) per row
    for (int e = threadIdx.x; e < 64 * 36; e += 512) {
        int nl = e / 36, c = e - nl * 36;
        fxtb[base + e] = pk2(tile[2 * c][nl], tile[2 * c + 1][nl]);
    }
    if (threadIdx.x < 64) {
        int n = n0 + threadIdx.x;
        float x = tile[64][threadIdx.x], y = tile[65][threadIdx.x], z = tile[66][threadIdx.x];
        pts4[(size_t)b * NN + n] = make_float4(x, y, z, x * x + y * y + z * z);
        if (n0 < PP) out2[b * PP + n] = (float)n;
    }
    if (n0 < PP) {
        for (int e = threadIdx.x; e < 64 * 3; e += 512) {
            int nl = e / 3, d = e - nl * 3;
            out0[((size_t)b * PP + n0 + nl) * 3 + d] = tile[64 + d][nl];
        }
    }
}

// ---------------- K23: fused KNN + MLP (block-local dependency) ----
// 256 blocks x 1024 thr, 1 block/CU. Wave wv owns queries q0base+wv*4..+3 for
// BOTH phases; knn indices stay in LDS (no global round-trip). b = blockIdx&7
// pins batch -> XCD so staging + gathers are XCD-L2-local.
// After KNN, the dead 128KB stage is overlaid with:
//   w1a [64]x104 shorts (bank classes (5c+q)%8: 8 disjoint-bank classes x 8 lanes)
//   w2  [128]x88 shorts (classes (3c+q)%8, same full-BW property)
//   h1  16 waves x [16][72] shorts,  otile [64][130] f32
__global__ __launch_bounds__(1024, 4) void k23(const float4* __restrict__ pts4,
                                               const unsigned* __restrict__ fxtb,
                                               const unsigned short* __restrict__ w1p,
                                               const unsigned short* __restrict__ w2p,
                                               const float* __restrict__ c1,
                                               const float* __restrict__ c2,
                                               float* __restrict__ out1) {
    __shared__ __align__(16) char smem[131072];
    __shared__ float2 scratch[16][2][64];    // 16 KB dual per-wave buffers
    __shared__ int knnl[16][64];             // 4 KB: per-wave [4 queries][16 ranks]
    int lane = threadIdx.x & 63;
    int wv   = threadIdx.x >> 6;
    int b    = blockIdx.x & 7;               // XCD-aware batch assignment
    int q0base = (blockIdx.x >> 3) * 64;
    size_t pb = (size_t)b * NN;

    // ================= Phase A: KNN =================
    {
        float4* stage = (float4*)smem;       // swizzled slot(r,c)=r*64+((c+(r>>1))&63)
        int q0 = q0base + wv * 4;

        float4 qc = make_float4(0.f, 0.f, 0.f, 0.f);
        if (lane < 4) qc = pts4[pb + q0 + lane];
        float qx2 = -2.f * qc.x, qy2 = -2.f * qc.y, qz2 = -2.f * qc.z;
        float bx[4], by[4], bz[4];
#pragma unroll
        for (int q = 0; q < 4; ++q) {
            bx[q] = __shfl(qx2, q); by[q] = __shfl(qy2, q); bz[q] = __shfl(qz2, q);
        }

#pragma unroll
        for (int i = 0; i < 8; ++i) {
            int p = i * 1024 + threadIdx.x;
            float4 v = pts4[pb + p];
            int r = p >> 6, c = p & 63;
            stage[(r << 6) | ((c + (r >> 1)) & 63)] = v;
        }
        __syncthreads();

        // Phase 1: per-lane min over its 128 candidates (rows 2L, 2L+1)
        float m[4];
#pragma unroll
        for (int q = 0; q < 4; ++q) m[q] = FLTMAX;
#pragma unroll
        for (int rr = 0; rr < 2; ++rr) {
            int rowbase = (2 * lane + rr) << 6;
#pragma unroll
            for (int j8 = 0; j8 < 8; ++j8) {
                float4 cc[8];
#pragma unroll
                for (int i = 0; i < 8; ++i)
                    cc[i] = stage[rowbase | ((j8 * 8 + i + lane) & 63)];
#pragma unroll
                for (int q = 0; q < 4; ++q) {
                    float x = bx[q], y = by[q], z = bz[q];
#pragma unroll
                    for (int i = 0; i < 8; i += 2) {
                        float e0 = fmaf(z, cc[i].z, fmaf(y, cc[i].y, fmaf(x, cc[i].x, cc[i].w)));
                        float e1 = fmaf(z, cc[i+1].z, fmaf(y, cc[i+1].y, fmaf(x, cc[i+1].x, cc[i+1].w)));
                        m[q] = fminf(fminf(m[q], e0), e1);
                    }
                }
            }
        }

        // Interleaved threshold sorts: T[q] = 16th smallest of 64 lane-mins
        float sv0 = m[0], sv1 = m[1], sv2 = m[2], sv3 = m[3];
#pragma unroll
        for (int k = 2; k <= 64; k <<= 1) {
#pragma unroll
            for (int j = k >> 1; j > 0; j >>= 1) {
                bool keepMin = (((lane & k) == 0) == ((lane & j) == 0));
                float p0 = __shfl_xor(sv0, j, 64);
                float p1 = __shfl_xor(sv1, j, 64);
                float p2 = __shfl_xor(sv2, j, 64);
                float p3 = __shfl_xor(sv3, j, 64);
                sv0 = keepMin ? fminf(sv0, p0) : fmaxf(sv0, p0);
                sv1 = keepMin ? fminf(sv1, p1) : fmaxf(sv1, p1);
                sv2 = keepMin ? fminf(sv2, p2) : fmaxf(sv2, p2);
                sv3 = keepMin ? fminf(sv3, p3) : fmaxf(sv3, p3);
            }
        }
        float T[4];
        T[0] = __shfl(sv0, 15, 64); T[1] = __shfl(sv1, 15, 64);
        T[2] = __shfl(sv2, 15, 64); T[3] = __shfl(sv3, 15, 64);

        unsigned long long below = (lane == 63) ? 0x7FFFFFFFFFFFFFFFull
                                                : ((1ull << lane) - 1ull);
#pragma unroll
        for (int pr = 0; pr < 4; pr += 2) {
            int Ms[2];
#pragma unroll
            for (int u = 0; u < 2; ++u) {
                int q = pr + u;
                float x = bx[q], y = by[q], z = bz[q], tq = T[q];
                unsigned long long rm = __ballot(m[q] <= tq);
                int cnt = 0;
                while (rm) {
                    int sl = __ffsll((long long)rm) - 1; rm &= rm - 1;
                    int phys = (lane + sl) & 63;
                    float4 c0 = stage[((2 * sl) << 6) | phys];
                    float4 c1v_ = stage[((2 * sl + 1) << 6) | phys];
                    float e0 = fmaf(z, c0.z, fmaf(y, c0.y, fmaf(x, c0.x, c0.w)));
                    float e1 = fmaf(z, c1v_.z, fmaf(y, c1v_.y, fmaf(x, c1v_.x, c1v_.w)));
                    unsigned long long b0 = __ballot(e0 <= tq);
                    if (e0 <= tq) {
                        int pos = cnt + __popcll(b0 & below);
                        if (pos < 64)
                            scratch[wv][u][pos] = make_float2(e0, __int_as_float(sl * 128 + lane));
                    }
                    cnt += __popcll(b0);
                    unsigned long long b1 = __ballot(e1 <= tq);
                    if (e1 <= tq) {
                        int pos = cnt + __popcll(b1 & below);
                        if (pos < 64)
                            scratch[wv][u][pos] = make_float2(e1, __int_as_float(sl * 128 + 64 + lane));
                    }
                    cnt += __popcll(b1);
                }
                Ms[u] = min(cnt, 64);
            }
            LDS_FENCE();   // drain compaction writes before readback
#pragma unroll
            for (int u = 0; u < 2; ++u) {
                int M = Ms[u];
                float2 own = scratch[wv][u][lane];
                float di = own.x; int ni = __float_as_int(own.y);
                int rank = 0;
                const float2* buf = &scratch[wv][u][0];
#pragma unroll 4
                for (int j = 0; j < M; ++j) {
                    float2 e = buf[j];
                    int nj = __float_as_int(e.y);
                    rank += (e.x < di || (e.x == di && nj < ni)) ? 1 : 0;
                }
                if (lane < M && rank < 16)
                    knnl[wv][(pr + u) * 16 + rank] = ni;   // LDS, not global
            }
            LDS_FENCE();   // order scratch reuse across pairs
        }
    }

    // all 64 knn indices for this wave's 4 queries (wave-local LDS)
    int idxAll = knnl[wv][lane];

    __syncthreads();   // stage buffer dead -> safe to overlay

    // ================= Phase B: MLP =================
    unsigned short* w1a   = (unsigned short*)smem;             // [64][104]
    unsigned short* w2l   = (unsigned short*)(smem + 13312);   // [128][88]
    unsigned short* h1all = (unsigned short*)(smem + 35840);   // 16 x [16][72]
    float*          otile = (float*)(smem + 72704);            // [64][130]
    int col = lane & 15, quad = lane >> 4;
    const uint4* fx4 = (const uint4*)fxtb;
    size_t rowb = (size_t)b * NN;

    // stage weights into LDS (all 1024 threads)
    {
        const unsigned* src1 = (const unsigned*)w1p;   // rows: 96 dw stride (192 shorts)
        unsigned* d1 = (unsigned*)w1a;
        for (int t = threadIdx.x; t < 64 * 48; t += 1024) {
            int r = t / 48, c = t - r * 48;
            d1[r * 52 + c] = src1[r * 96 + c];
        }
        const unsigned* src2 = (const unsigned*)w2p;   // rows: 36 dw
        unsigned* d2 = (unsigned*)w2l;
        for (int t = threadIdx.x; t < 128 * 36; t += 1024) {
            int r = t / 36, c = t - r * 36;
            d2[r * 44 + c] = src2[r * 36 + c];
        }
    }

    // qterm: f_q . W1d for this wave's 4 queries (W1d fragments from global, used once)
    f32x4 accq[4];
#pragma unroll
    for (int nt = 0; nt < 4; ++nt) accq[nt] = (f32x4){0.f, 0.f, 0.f, 0.f};
    {
        const uint4* rp = fx4 + (rowb + q0base + wv * 4 + col) * 9;
        uint4 qf0 = rp[quad];
        uint4 qf1 = rp[4 + quad];
        uint4 qf2 = rp[8];
        if (quad != 0) qf2 = make_uint4(0u, 0u, 0u, 0u);
        uint4 qf[3] = {qf0, qf1, qf2};
#pragma unroll
        for (int ks = 0; ks < 3; ++ks) {
            s16x8 a = as8(qf[ks]);
#pragma unroll
            for (int nt = 0; nt < 4; ++nt) {
                s16x8 bfr = *(const s16x8*)(w1p + (nt * 16 + col) * 192 + 96 + ks * 32 + quad * 8);
                accq[nt] = __builtin_amdgcn_mfma_f32_16x16x32_bf16(a, bfr, accq[nt], 0, 0, 0);
            }
        }
    }
    float qcc[4][4];   // qterm + c1, per (query, nt)
    {
        float c1v[4];
#pragma unroll
        for (int nt = 0; nt < 4; ++nt) c1v[nt] = c1[nt * 16 + col];
#pragma unroll
        for (int qi = 0; qi < 4; ++qi)
#pragma unroll
            for (int nt = 0; nt < 4; ++nt)
                qcc[qi][nt] = __shfl(accq[nt][qi], col, 64) + c1v[nt];
    }
    float c2v[8];
#pragma unroll
    for (int nt = 0; nt < 8; ++nt) c2v[nt] = c2[nt * 16 + col];

    __syncthreads();   // staged weights visible to all waves

    unsigned short* h1w = h1all + wv * (16 * K2PAD);

    uint4 af[2][3];
#define PREF(buf, qi_) {                                                      \
        int nidx_ = __shfl(idxAll, (qi_) * 16 + col, 64);                     \
        const uint4* rp_ = fx4 + (rowb + nidx_) * 9;                          \
        af[buf][0] = rp_[quad];                                               \
        af[buf][1] = rp_[4 + quad];                                           \
        uint4 f2_ = rp_[8];                                                   \
        af[buf][2] = (quad == 0) ? f2_ : make_uint4(0u, 0u, 0u, 0u); }

    PREF(0, 0);

#pragma unroll
    for (int qi = 0; qi < 4; ++qi) {
        const int cur = qi & 1;
        // GEMM1: A = gathered rows (regs), B = w1a (LDS), acc init = qterm + c1
        f32x4 acc1[4];
#pragma unroll
        for (int nt = 0; nt < 4; ++nt)
            acc1[nt] = (f32x4){qcc[qi][nt], qcc[qi][nt], qcc[qi][nt], qcc[qi][nt]};
#pragma unroll
        for (int ks = 0; ks < 3; ++ks) {
            s16x8 a = as8(af[cur][ks]);
#pragma unroll
            for (int nt = 0; nt < 4; ++nt) {
                s16x8 bfr = *(const s16x8*)(w1a + (nt * 16 + col) * 104 + ks * 32 + quad * 8);
                acc1[nt] = __builtin_amdgcn_mfma_f32_16x16x32_bf16(a, bfr, acc1[nt], 0, 0, 0);
            }
        }
        // kick next query's gather while h1/GEMM2 run
        if (qi < 3) PREF(cur ^ 1, qi + 1);
        // h1 = relu(acc1) -> LDS (wave-private)
#pragma unroll
        for (int nt = 0; nt < 4; ++nt)
#pragma unroll
            for (int rr = 0; rr < 4; ++rr)
                h1w[(quad * 4 + rr) * K2PAD + nt * 16 + col] = bf16b(fmaxf(acc1[nt][rr], 0.f));
        LDS_FENCE();
        // GEMM2 + maxpool, split into two nt-halves (VGPR <= 128 budget)
#pragma unroll
        for (int hf = 0; hf < 2; ++hf) {
            f32x4 acc2[4];
#pragma unroll
            for (int nt = 0; nt < 4; ++nt) acc2[nt] = (f32x4){0.f, 0.f, 0.f, 0.f};
#pragma unroll
            for (int ks = 0; ks < 2; ++ks) {
                s16x8 a2 = *(const s16x8*)(h1w + col * K2PAD + ks * 32 + quad * 8);
#pragma unroll
                for (int nt = 0; nt < 4; ++nt) {
                    s16x8 wf = *(const s16x8*)(w2l + ((hf * 4 + nt) * 16 + col) * 88 + ks * 32 + quad * 8);
                    acc2[nt] = __builtin_amdgcn_mfma_f32_16x16x32_bf16(a2, wf, acc2[nt], 0, 0, 0);
                }
            }
#pragma unroll
            for (int nt = 0; nt < 4; ++nt) {
                float m0 = fmaxf(fmaxf(acc2[nt][0], acc2[nt][1]), fmaxf(acc2[nt][2], acc2[nt][3]));
                m0 = fmaxf(m0 + c2v[hf * 4 + nt], 0.f);
                m0 = fmaxf(m0, __shfl_xor(m0, 16, 64));
                m0 = fmaxf(m0, __shfl_xor(m0, 32, 64));
                if (quad == 0)
                    otile[(wv * 4 + qi) * 130 + (hf * 4 + nt) * 16 + col] = m0;
            }
        }
        LDS_FENCE();   // drain h1 reads before next iteration's overwrite
    }
    __syncthreads();
    // coalesced store: consecutive threads -> consecutive q, same channel
    for (int i = threadIdx.x; i < H2 * 64; i += 1024) {
        int ch = i >> 6, q = i & 63;
        out1[((size_t)(b * H2 + ch)) * PP + q0base + q] = otile[q * 130 + ch];
    }
#undef PREF
}

extern "C" void kernel_launch(void* const* d_in, const int* in_sizes, int n_in,
                              void* d_out, int out_size, void* d_ws, size_t ws_size,
                              hipStream_t stream) {
    const float* xyz  = (const float*)d_in[0];
    const float* feat = (const float*)d_in[1];
    const float* W1   = (const float*)d_in[2];
    const float* b1   = (const float*)d_in[3];
    const float* g1   = (const float*)d_in[4];
    const float* be1  = (const float*)d_in[5];
    const float* m1   = (const float*)d_in[6];
    const float* v1   = (const float*)d_in[7];
    const float* W2   = (const float*)d_in[8];
    const float* b2   = (const float*)d_in[9];
    const float* g2   = (const float*)d_in[10];
    const float* be2  = (const float*)d_in[11];
    const float* m2   = (const float*)d_in[12];
    const float* v2   = (const float*)d_in[13];

    char* ws = (char*)d_ws;
    unsigned*       fxtb = (unsigned*)(ws + OFF_FXT);
    float4*         pts4 = (float4*)(ws + OFF_PTS4);
    unsigned short* w1p  = (unsigned short*)(ws + OFF_W1P);
    unsigned short* w2p  = (unsigned short*)(ws + OFF_W2P);
    float*          c1   = (float*)(ws + OFF_C1);
    float*          c2   = (float*)(ws + OFF_C2);

    float* out0 = (float*)d_out;
    float* out1 = out0 + (size_t)BB * PP * 3;
    float* out2 = out1 + (size_t)BB * H2 * PP;

    hipLaunchKernelGGL(k1_prep, dim3(1024), dim3(512), 0, stream,
                       xyz, feat, fxtb, pts4, out0, out2,
                       W1, b1, g1, be1, m1, v1, W2, b2, g2, be2, m2, v2,
                       w1p, w2p, c1, c2);
    hipLaunchKernelGGL(k23, dim3(256), dim3(1024), 0, stream,
                       pts4, fxtb, w1p, w2p, c1, c2, out1);
}

// Round 3
// 153.485 us; speedup vs baseline: 1.0819x; 1.0117x over previous
//
#include <hip/hip_runtime.h>
#include <hip/hip_bf16.h>

// Problem constants
#define BB 8
#define NN 8192
#define CC 64
#define PP 2048
#define KK 16
#define H1 64
#define H2 128
#define K2PAD 72

typedef float  f32x4 __attribute__((ext_vector_type(4)));
typedef short  s16x8 __attribute__((ext_vector_type(8)));

// ---- workspace layout (bytes) ----
#define OFF_FXT   0u
#define OFF_PTS4  17825792u             // B*N float4 = 2,097,152
#define OFF_W1P   20971520u             // 64*192 bf16 ([n][0:96)=W1a*s, [n][96:192)=(W1b-W1a)*s)
#define OFF_W2P   20996096u             // 128*72 bf16
#define OFF_C1    21014528u             // 64 f32
#define OFF_C2    21014784u             // 128 f32

#define FLTMAX 3.402823466e+38f

static __device__ __forceinline__ unsigned short bf16b(float v) {
    __hip_bfloat16 h = __float2bfloat16(v);
    return *reinterpret_cast<unsigned short*>(&h);
}
static __device__ __forceinline__ unsigned pk2(float a, float b) {
    return ((unsigned)bf16b(b) << 16) | (unsigned)bf16b(a);
}
static __device__ __forceinline__ s16x8 as8(uint4 v) {
    union { uint4 u; s16x8 s; } x; x.u = v; return x.s;
}
// wave-local LDS fence: compiler barrier + LDS drain, NO vmcnt drain
#define LDS_FENCE() asm volatile("s_waitcnt lgkmcnt(0)" ::: "memory")

// ---------------- K1: transpose feat -> fxtb, pts4, outs, weight fold ----
__global__ __launch_bounds__(512) void k1_prep(const float* __restrict__ xyz,
                                               const float* __restrict__ feat,
                                               unsigned* __restrict__ fxtb,
                                               float4* __restrict__ pts4,
                                               float* __restrict__ out0,
                                               float* __restrict__ out2,
                                               const float* __restrict__ W1, const float* __restrict__ b1,
                                               const float* __restrict__ g1, const float* __restrict__ be1,
                                               const float* __restrict__ m1, const float* __restrict__ v1,
                                               const float* __restrict__ W2, const float* __restrict__ b2,
                                               const float* __restrict__ g2, const float* __restrict__ be2,
                                               const float* __restrict__ m2, const float* __restrict__ v2,
                                               unsigned short* __restrict__ w1p,
                                               unsigned short* __restrict__ w2p,
                                               float* __restrict__ c1, float* __restrict__ c2) {
    __shared__ float tile[72][65];
    // weight fold slice (21,696 elems over blocks 0..255), hidden in k1 latency
    if (blockIdx.x < 256 && threadIdx.x < 85) {
        int i = blockIdx.x * 85 + threadIdx.x;
        if (i < 6144) {                      // W1a folded: [64][96]
            int n = i / 96, c = i - n * 96;
            float s = g1[n] * rsqrtf(v1[n] + 1e-5f);
            w1p[n * 192 + c] = bf16b((c < 67) ? W1[n * 134 + c] * s : 0.f);
        } else if (i < 12288) {              // W1d = (W1b-W1a)*s: [64][96] at +96
            int j = i - 6144;
            int n = j / 96, c = j - n * 96;
            float s = g1[n] * rsqrtf(v1[n] + 1e-5f);
            w1p[n * 192 + 96 + c] =
                bf16b((c < 67) ? (W1[n * 134 + 67 + c] - W1[n * 134 + c]) * s : 0.f);
        } else if (i < 21504) {              // W2 folded: [128][72]
            int j = i - 12288;
            int o = j / 72, k = j - o * 72;
            float s = g2[o] * rsqrtf(v2[o] + 1e-5f);
            w2p[j] = bf16b((k < 64) ? W2[o * 64 + k] * s : 0.f);
        } else if (i < 21568) {
            int l = i - 21504;
            float s = g1[l] * rsqrtf(v1[l] + 1e-5f);
            c1[l] = s * (b1[l] - m1[l]) + be1[l];
        } else if (i < 21696) {
            int p = i - 21568;
            float s = g2[p] * rsqrtf(v2[p] + 1e-5f);
            c2[p] = s * (b2[p] - m2[p]) + be2[p];
        }
    }
    int b  = blockIdx.x >> 7;
    int n0 = (blockIdx.x & 127) * 64;
    int tx = threadIdx.x & 63, ty = threadIdx.x >> 6;
    for (int c = ty; c < 72; c += 8) {
        float v;
        if (c < 64)       v = feat[((size_t)b * 64 + c) * NN + n0 + tx];
        else if (c < 67)  v = xyz[((size_t)b * NN + n0 + tx) * 3 + (c - 64)];
        else              v = 0.f;                 // pad cols 67..71
        tile[c][tx] = v;
    }
    __syncthreads();
    size_t base = ((size_t)b * NN + n0) * 36;      // 36 dwords (72 bf16) per row
    for (int e = threadIdx.x; e < 64 * 36; e += 512) {
        int nl = e / 36, c = e - nl * 36;
        fxtb[base + e] = pk2(tile[2 * c][nl], tile[2 * c + 1][nl]);
    }
    if (threadIdx.x < 64) {
        int n = n0 + threadIdx.x;
        float x = tile[64][threadIdx.x], y = tile[65][threadIdx.x], z = tile[66][threadIdx.x];
        pts4[(size_t)b * NN + n] = make_float4(x, y, z, x * x + y * y + z * z);
        if (n0 < PP) out2[b * PP + n] = (float)n;
    }
    if (n0 < PP) {
        for (int e = threadIdx.x; e < 64 * 3; e += 512) {
            int nl = e / 3, d = e - nl * 3;
            out0[((size_t)b * PP + n0 + nl) * 3 + d] = tile[64 + d][nl];
        }
    }
}

// ---------------- K23: fused KNN + MLP (block-local dependency) ----
// 256 blocks x 1024 thr, 1 block/CU (LDS-bound). launch_bounds(1024,1):
// min 1 block/CU -> VGPR cap 128 (the (1024,4) variant capped at 64 and
// spilled Phase B to scratch: 88us, VALUBusy 39%). Wave wv owns queries
// q0base+wv*4..+3 for BOTH phases; knn indices stay in LDS. b = blockIdx&7
// pins batch -> XCD so staging + gathers are XCD-L2-local.
// After KNN, the dead 128KB stage is overlaid with:
//   w1a [64]x104 shorts ((5c+q)%8 bank classes, reads <=2-way)
//   w2  [128]x88 shorts ((3c+q)%8, same), h1 16x[16][72], otile [64][130]
__global__ __launch_bounds__(1024, 1) void k23(const float4* __restrict__ pts4,
                                               const unsigned* __restrict__ fxtb,
                                               const unsigned short* __restrict__ w1p,
                                               const unsigned short* __restrict__ w2p,
                                               const float* __restrict__ c1,
                                               const float* __restrict__ c2,
                                               float* __restrict__ out1) {
    __shared__ __align__(16) char smem[131072];
    __shared__ float2 scratch[16][2][64];    // 16 KB dual per-wave buffers
    __shared__ int knnl[16][64];             // 4 KB: per-wave [4 queries][16 ranks]
    int lane = threadIdx.x & 63;
    int wv   = threadIdx.x >> 6;
    int b    = blockIdx.x & 7;               // XCD-aware batch assignment
    int q0base = (blockIdx.x >> 3) * 64;
    size_t pb = (size_t)b * NN;

    // ================= Phase A: KNN =================
    {
        float4* stage = (float4*)smem;       // swizzled slot(r,c)=r*64+((c+(r>>1))&63)
        int q0 = q0base + wv * 4;

        float4 qc = make_float4(0.f, 0.f, 0.f, 0.f);
        if (lane < 4) qc = pts4[pb + q0 + lane];
        float qx2 = -2.f * qc.x, qy2 = -2.f * qc.y, qz2 = -2.f * qc.z;
        float bx[4], by[4], bz[4];
#pragma unroll
        for (int q = 0; q < 4; ++q) {
            bx[q] = __shfl(qx2, q); by[q] = __shfl(qy2, q); bz[q] = __shfl(qz2, q);
        }

#pragma unroll
        for (int i = 0; i < 8; ++i) {
            int p = i * 1024 + threadIdx.x;
            float4 v = pts4[pb + p];
            int r = p >> 6, c = p & 63;
            stage[(r << 6) | ((c + (r >> 1)) & 63)] = v;
        }
        __syncthreads();

        // Phase 1: per-lane min over its 128 candidates (rows 2L, 2L+1)
        float m[4];
#pragma unroll
        for (int q = 0; q < 4; ++q) m[q] = FLTMAX;
#pragma unroll
        for (int rr = 0; rr < 2; ++rr) {
            int rowbase = (2 * lane + rr) << 6;
#pragma unroll
            for (int j8 = 0; j8 < 8; ++j8) {
                float4 cc[8];
#pragma unroll
                for (int i = 0; i < 8; ++i)
                    cc[i] = stage[rowbase | ((j8 * 8 + i + lane) & 63)];
#pragma unroll
                for (int q = 0; q < 4; ++q) {
                    float x = bx[q], y = by[q], z = bz[q];
#pragma unroll
                    for (int i = 0; i < 8; i += 2) {
                        float e0 = fmaf(z, cc[i].z, fmaf(y, cc[i].y, fmaf(x, cc[i].x, cc[i].w)));
                        float e1 = fmaf(z, cc[i+1].z, fmaf(y, cc[i+1].y, fmaf(x, cc[i+1].x, cc[i+1].w)));
                        m[q] = fminf(fminf(m[q], e0), e1);
                    }
                }
            }
        }

        // Interleaved threshold sorts: T[q] = 16th smallest of 64 lane-mins
        float sv0 = m[0], sv1 = m[1], sv2 = m[2], sv3 = m[3];
#pragma unroll
        for (int k = 2; k <= 64; k <<= 1) {
#pragma unroll
            for (int j = k >> 1; j > 0; j >>= 1) {
                bool keepMin = (((lane & k) == 0) == ((lane & j) == 0));
                float p0 = __shfl_xor(sv0, j, 64);
                float p1 = __shfl_xor(sv1, j, 64);
                float p2 = __shfl_xor(sv2, j, 64);
                float p3 = __shfl_xor(sv3, j, 64);
                sv0 = keepMin ? fminf(sv0, p0) : fmaxf(sv0, p0);
                sv1 = keepMin ? fminf(sv1, p1) : fmaxf(sv1, p1);
                sv2 = keepMin ? fminf(sv2, p2) : fmaxf(sv2, p2);
                sv3 = keepMin ? fminf(sv3, p3) : fmaxf(sv3, p3);
            }
        }
        float T[4];
        T[0] = __shfl(sv0, 15, 64); T[1] = __shfl(sv1, 15, 64);
        T[2] = __shfl(sv2, 15, 64); T[3] = __shfl(sv3, 15, 64);

        unsigned long long below = (lane == 63) ? 0x7FFFFFFFFFFFFFFFull
                                                : ((1ull << lane) - 1ull);
#pragma unroll
        for (int pr = 0; pr < 4; pr += 2) {
            int Ms[2];
#pragma unroll
            for (int u = 0; u < 2; ++u) {
                int q = pr + u;
                float x = bx[q], y = by[q], z = bz[q], tq = T[q];
                unsigned long long rm = __ballot(m[q] <= tq);
                int cnt = 0;
                while (rm) {
                    int sl = __ffsll((long long)rm) - 1; rm &= rm - 1;
                    int phys = (lane + sl) & 63;
                    float4 c0 = stage[((2 * sl) << 6) | phys];
                    float4 c1v_ = stage[((2 * sl + 1) << 6) | phys];
                    float e0 = fmaf(z, c0.z, fmaf(y, c0.y, fmaf(x, c0.x, c0.w)));
                    float e1 = fmaf(z, c1v_.z, fmaf(y, c1v_.y, fmaf(x, c1v_.x, c1v_.w)));
                    unsigned long long b0 = __ballot(e0 <= tq);
                    if (e0 <= tq) {
                        int pos = cnt + __popcll(b0 & below);
                        if (pos < 64)
                            scratch[wv][u][pos] = make_float2(e0, __int_as_float(sl * 128 + lane));
                    }
                    cnt += __popcll(b0);
                    unsigned long long b1 = __ballot(e1 <= tq);
                    if (e1 <= tq) {
                        int pos = cnt + __popcll(b1 & below);
                        if (pos < 64)
                            scratch[wv][u][pos] = make_float2(e1, __int_as_float(sl * 128 + 64 + lane));
                    }
                    cnt += __popcll(b1);
                }
                Ms[u] = min(cnt, 64);
            }
            LDS_FENCE();   // drain compaction writes before readback
#pragma unroll
            for (int u = 0; u < 2; ++u) {
                int M = Ms[u];
                float2 own = scratch[wv][u][lane];
                float di = own.x; int ni = __float_as_int(own.y);
                int rank = 0;
                const float2* buf = &scratch[wv][u][0];
#pragma unroll 4
                for (int j = 0; j < M; ++j) {
                    float2 e = buf[j];
                    int nj = __float_as_int(e.y);
                    rank += (e.x < di || (e.x == di && nj < ni)) ? 1 : 0;
                }
                if (lane < M && rank < 16)
                    knnl[wv][(pr + u) * 16 + rank] = ni;   // LDS, not global
            }
            LDS_FENCE();   // order scratch reuse across pairs
        }
    }

    // all 64 knn indices for this wave's 4 queries (wave-local LDS)
    int idxAll = knnl[wv][lane];

    __syncthreads();   // stage buffer dead -> safe to overlay

    // ================= Phase B: MLP =================
    unsigned short* w1a   = (unsigned short*)smem;             // [64][104]
    unsigned short* w2l   = (unsigned short*)(smem + 13312);   // [128][88]
    unsigned short* h1all = (unsigned short*)(smem + 35840);   // 16 x [16][72]
    float*          otile = (float*)(smem + 72704);            // [64][130]
    int col = lane & 15, quad = lane >> 4;
    const uint4* fx4 = (const uint4*)fxtb;
    size_t rowb = (size_t)b * NN;

    // stage weights into LDS (all 1024 threads)
    {
        const unsigned* src1 = (const unsigned*)w1p;   // rows: 96 dw stride (192 shorts)
        unsigned* d1 = (unsigned*)w1a;
        for (int t = threadIdx.x; t < 64 * 48; t += 1024) {
            int r = t / 48, c = t - r * 48;
            d1[r * 52 + c] = src1[r * 96 + c];
        }
        const unsigned* src2 = (const unsigned*)w2p;   // rows: 36 dw
        unsigned* d2 = (unsigned*)w2l;
        for (int t = threadIdx.x; t < 128 * 36; t += 1024) {
            int r = t / 36, c = t - r * 36;
            d2[r * 44 + c] = src2[r * 36 + c];
        }
    }

    // qterm: f_q . W1d for this wave's 4 queries (W1d fragments from global, used once)
    f32x4 accq[4];
#pragma unroll
    for (int nt = 0; nt < 4; ++nt) accq[nt] = (f32x4){0.f, 0.f, 0.f, 0.f};
    {
        const uint4* rp = fx4 + (rowb + q0base + wv * 4 + col) * 9;
        uint4 qf0 = rp[quad];
        uint4 qf1 = rp[4 + quad];
        uint4 qf2 = rp[8];
        if (quad != 0) qf2 = make_uint4(0u, 0u, 0u, 0u);
        uint4 qf[3] = {qf0, qf1, qf2};
#pragma unroll
        for (int ks = 0; ks < 3; ++ks) {
            s16x8 a = as8(qf[ks]);
#pragma unroll
            for (int nt = 0; nt < 4; ++nt) {
                s16x8 bfr = *(const s16x8*)(w1p + (nt * 16 + col) * 192 + 96 + ks * 32 + quad * 8);
                accq[nt] = __builtin_amdgcn_mfma_f32_16x16x32_bf16(a, bfr, accq[nt], 0, 0, 0);
            }
        }
    }
    float qcc[4][4];   // qterm + c1, per (query, nt)
    {
        float c1v[4];
#pragma unroll
        for (int nt = 0; nt < 4; ++nt) c1v[nt] = c1[nt * 16 + col];
#pragma unroll
        for (int qi = 0; qi < 4; ++qi)
#pragma unroll
            for (int nt = 0; nt < 4; ++nt)
                qcc[qi][nt] = __shfl(accq[nt][qi], col, 64) + c1v[nt];
    }
    float c2v[8];
#pragma unroll
    for (int nt = 0; nt < 8; ++nt) c2v[nt] = c2[nt * 16 + col];

    __syncthreads();   // staged weights visible to all waves

    unsigned short* h1w = h1all + wv * (16 * K2PAD);

    uint4 af[2][3];
#define PREF(buf, qi_) {                                                      \
        int nidx_ = __shfl(idxAll, (qi_) * 16 + col, 64);                     \
        const uint4* rp_ = fx4 + (rowb + nidx_) * 9;                          \
        af[buf][0] = rp_[quad];                                               \
        af[buf][1] = rp_[4 + quad];                                           \
        uint4 f2_ = rp_[8];                                                   \
        af[buf][2] = (quad == 0) ? f2_ : make_uint4(0u, 0u, 0u, 0u); }

    PREF(0, 0);

#pragma unroll
    for (int qi = 0; qi < 4; ++qi) {
        const int cur = qi & 1;
        // GEMM1: A = gathered rows (regs), B = w1a (LDS), acc init = qterm + c1
        f32x4 acc1[4];
#pragma unroll
        for (int nt = 0; nt < 4; ++nt)
            acc1[nt] = (f32x4){qcc[qi][nt], qcc[qi][nt], qcc[qi][nt], qcc[qi][nt]};
#pragma unroll
        for (int ks = 0; ks < 3; ++ks) {
            s16x8 a = as8(af[cur][ks]);
#pragma unroll
            for (int nt = 0; nt < 4; ++nt) {
                s16x8 bfr = *(const s16x8*)(w1a + (nt * 16 + col) * 104 + ks * 32 + quad * 8);
                acc1[nt] = __builtin_amdgcn_mfma_f32_16x16x32_bf16(a, bfr, acc1[nt], 0, 0, 0);
            }
        }
        // kick next query's gather while h1/GEMM2 run
        if (qi < 3) PREF(cur ^ 1, qi + 1);
        // h1 = relu(acc1) -> LDS (wave-private)
#pragma unroll
        for (int nt = 0; nt < 4; ++nt)
#pragma unroll
            for (int rr = 0; rr < 4; ++rr)
                h1w[(quad * 4 + rr) * K2PAD + nt * 16 + col] = bf16b(fmaxf(acc1[nt][rr], 0.f));
        LDS_FENCE();
        // GEMM2 + maxpool, split into two nt-halves (register pressure)
#pragma unroll
        for (int hf = 0; hf < 2; ++hf) {
            f32x4 acc2[4];
#pragma unroll
            for (int nt = 0; nt < 4; ++nt) acc2[nt] = (f32x4){0.f, 0.f, 0.f, 0.f};
#pragma unroll
            for (int ks = 0; ks < 2; ++ks) {
                s16x8 a2 = *(const s16x8*)(h1w + col * K2PAD + ks * 32 + quad * 8);
#pragma unroll
                for (int nt = 0; nt < 4; ++nt) {
                    s16x8 wf = *(const s16x8*)(w2l + ((hf * 4 + nt) * 16 + col) * 88 + ks * 32 + quad * 8);
                    acc2[nt] = __builtin_amdgcn_mfma_f32_16x16x32_bf16(a2, wf, acc2[nt], 0, 0, 0);
                }
            }
#pragma unroll
            for (int nt = 0; nt < 4; ++nt) {
                float m0 = fmaxf(fmaxf(acc2[nt][0], acc2[nt][1]), fmaxf(acc2[nt][2], acc2[nt][3]));
                m0 = fmaxf(m0 + c2v[hf * 4 + nt], 0.f);
                m0 = fmaxf(m0, __shfl_xor(m0, 16, 64));
                m0 = fmaxf(m0, __shfl_xor(m0, 32, 64));
                if (quad == 0)
                    otile[(wv * 4 + qi) * 130 + (hf * 4 + nt) * 16 + col] = m0;
            }
        }
        LDS_FENCE();   // drain h1 reads before next iteration's overwrite
    }
    __syncthreads();
    // coalesced store: consecutive threads -> consecutive q, same channel
    for (int i = threadIdx.x; i < H2 * 64; i += 1024) {
        int ch = i >> 6, q = i & 63;
        out1[((size_t)(b * H2 + ch)) * PP + q0base + q] = otile[q * 130 + ch];
    }
#undef PREF
}

extern "C" void kernel_launch(void* const* d_in, const int* in_sizes, int n_in,
                              void* d_out, int out_size, void* d_ws, size_t ws_size,
                              hipStream_t stream) {
    const float* xyz  = (const float*)d_in[0];
    const float* feat = (const float*)d_in[1];
    const float* W1   = (const float*)d_in[2];
    const float* b1   = (const float*)d_in[3];
    const float* g1   = (const float*)d_in[4];
    const float* be1  = (const float*)d_in[5];
    const float* m1   = (const float*)d_in[6];
    const float* v1   = (const float*)d_in[7];
    const float* W2   = (const float*)d_in[8];
    const float* b2   = (const float*)d_in[9];
    const float* g2   = (const float*)d_in[10];
    const float* be2  = (const float*)d_in[11];
    const float* m2   = (const float*)d_in[12];
    const float* v2   = (const float*)d_in[13];

    char* ws = (char*)d_ws;
    unsigned*       fxtb = (unsigned*)(ws + OFF_FXT);
    float4*         pts4 = (float4*)(ws + OFF_PTS4);
    unsigned short* w1p  = (unsigned short*)(ws + OFF_W1P);
    unsigned short* w2p  = (unsigned short*)(ws + OFF_W2P);
    float*          c1   = (float*)(ws + OFF_C1);
    float*          c2   = (float*)(ws + OFF_C2);

    float* out0 = (float*)d_out;
    float* out1 = out0 + (size_t)BB * PP * 3;
    float* out2 = out1 + (size_t)BB * H2 * PP;

    hipLaunchKernelGGL(k1_prep, dim3(1024), dim3(512), 0, stream,
                       xyz, feat, fxtb, pts4, out0, out2,
                       W1, b1, g1, be1, m1, v1, W2, b2, g2, be2, m2, v2,
                       w1p, w2p, c1, c2);
    hipLaunchKernelGGL(k23, dim3(256), dim3(1024), 0, stream,
                       pts4, fxtb, w1p, w2p, c1, c2, out1);
}